// Round 19
// baseline (1257.231 us; speedup 1.0000x reference)
//
#include <hip/hip_runtime.h>
#include <stdint.h>

#define NB 64
#define BATCH 2
#define SEQ 1024
#define DMODEL 512
#define NHEAD 8
#define DHEAD 64
#define FDIM 2048
#define NLAYER 12
#define VOCAB 1024
#define KTOT (NB + SEQ)          // 1088
#define RSUM (BATCH * NB)        // 128
#define RREG (BATCH * SEQ)       // 2048
#define RTOT (RSUM + RREG)       // 2176

using bf16x8 = __attribute__((ext_vector_type(8))) short;
using bf16x4 = __attribute__((ext_vector_type(4))) short;
using f32x4  = __attribute__((ext_vector_type(4))) float;

__device__ __forceinline__ unsigned short f2bf(float f) {
  union { float f; unsigned u; } c; c.f = f;
  return (unsigned short)((c.u + 0x7fffu + ((c.u >> 16) & 1u)) >> 16);
}
__device__ __forceinline__ float bf2f(unsigned short s) {
  union { unsigned u; float f; } c; c.u = ((unsigned)s) << 16;
  return c.f;
}

// ---- async global->LDS staging of an R x 64-bf16 tile --------------------
// LDS layout linear [R][64]; source pre-swizzled: LDS slot j of row r holds
// global chunk (j ^ (r&7)) (16B chunks). Reads undo the XOR -> conflict-free.
template<int R>
__device__ __forceinline__ void stage_tile(
    const unsigned short* __restrict__ G, int K, int base_row, int k0,
    unsigned short (*lds)[64], int wid, int lane)
{
  const int rl = lane >> 3;
  const int j  = lane & 7;
  #pragma unroll
  for (int c = 0; c < R / 32; ++c) {
    const int r0 = wid * (R / 4) + c * 8;          // wave-uniform
    const int row = r0 + rl;
    const unsigned short* g = G + (size_t)(base_row + row) * K + k0
                                + ((j ^ (row & 7)) << 3);
    __builtin_amdgcn_global_load_lds(
        (const __attribute__((address_space(1))) void*)g,
        (__attribute__((address_space(3))) void*)&lds[r0][0], 16, 0, 0);
  }
}

__device__ __forceinline__ bf16x8 lds_frag(const unsigned short (*lds)[64],
                                           int row, int cc) {
  return *(const bf16x8*)&lds[row][(cc ^ (row & 7)) << 3];
}

// ---------------- GEMM: C[M,N] (+resid) = A[M,K]bf16 @ BT[N,K]bf16^T ------
// Small tiles, 256 threads -> many blocks/CU: latency hides via occupancy.
// PIPE: double-buffered LDS; STAGE(t+1) issued before compute(t).
// Dual-stream: M-tiles with bm < RSUM (summary rows) use B0, others B1.
// EPI: 0 = fp32 (+optional resid), 1 = SwiGLU->bf16 (w1/w3 interleaved,
// row stride N/2), 2 = bf16, 3 = fused RoPE+scatter to q/k/v_cat (BM=BN=64,
// head-aligned tiles; C tile staged via LDS to pair d with d^32).
template<int BM, int BN, int EPI, bool PIPE>
__global__ __launch_bounds__(256) void gemm_bt(
    const unsigned short* __restrict__ A, const unsigned short* __restrict__ B0,
    const unsigned short* __restrict__ B1,
    void* __restrict__ Cout, const float* resid, int N, int K,
    const float* __restrict__ cost, const float* __restrict__ sint,
    unsigned short* __restrict__ kcat, unsigned short* __restrict__ vcat)
{
  constexpr int BK = 64;
  constexpr int WM = BM / 2, WN = BN / 2;
  constexpr int FM = WM / 16, FN = WN / 16;
  constexpr int HALF = (BM + BN) * BK * 2;
  constexpr int SM_STAGE = (PIPE ? 2 : 1) * HALF;
  constexpr int SM_CT = (EPI == 3) ? 64 * 66 * 4 : 0;
  constexpr int SMSZ = SM_STAGE > SM_CT ? SM_STAGE : SM_CT;
  __shared__ __align__(16) unsigned char smem[SMSZ];
  const int bm = blockIdx.y * BM, bn = blockIdx.x * BN;
  const unsigned short* __restrict__ BT = (bm < RSUM) ? B0 : B1;
  const int tid = threadIdx.x;
  const int wid = tid >> 6, lane = tid & 63;
  const int wm = wid >> 1, wn = wid & 1;
  const int lr = lane & 15, lk = lane >> 4;
  f32x4 acc[FM][FN] = {};
  if constexpr (PIPE) {
    auto AsB = [&](int b) { return (unsigned short (*)[BK])(smem + b * HALF); };
    auto BsB = [&](int b) { return (unsigned short (*)[BK])(smem + b * HALF + BM * BK * 2); };
    stage_tile<BM>(A, K, bm, 0, AsB(0), wid, lane);
    stage_tile<BN>(BT, K, bn, 0, BsB(0), wid, lane);
    __syncthreads();
    int cur = 0;
    for (int k0 = 0; k0 < K; k0 += BK) {
      if (k0 + BK < K) {
        stage_tile<BM>(A, K, bm, k0 + BK, AsB(cur ^ 1), wid, lane);
        stage_tile<BN>(BT, K, bn, k0 + BK, BsB(cur ^ 1), wid, lane);
      }
      #pragma unroll
      for (int kk = 0; kk < 2; ++kk) {
        bf16x8 af[FM], bfr[FN];
        #pragma unroll
        for (int m = 0; m < FM; ++m)
          af[m] = lds_frag(AsB(cur), wm * WM + m * 16 + lr, kk * 4 + lk);
        #pragma unroll
        for (int n = 0; n < FN; ++n)
          bfr[n] = lds_frag(BsB(cur), wn * WN + n * 16 + lr, kk * 4 + lk);
        #pragma unroll
        for (int m = 0; m < FM; ++m)
          #pragma unroll
          for (int n = 0; n < FN; ++n)
            acc[m][n] = __builtin_amdgcn_mfma_f32_16x16x32_bf16(af[m], bfr[n], acc[m][n], 0, 0, 0);
      }
      __syncthreads();               // drains prefetch + LDS reads of cur
      cur ^= 1;
    }
  } else {
    auto As = (unsigned short (*)[BK])smem;
    auto Bs = (unsigned short (*)[BK])(smem + BM * BK * 2);
    for (int k0 = 0; k0 < K; k0 += BK) {
      __syncthreads();
      stage_tile<BM>(A, K, bm, k0, As, wid, lane);
      stage_tile<BN>(BT, K, bn, k0, Bs, wid, lane);
      __syncthreads();               // drains vmcnt -> tile ready
      #pragma unroll
      for (int kk = 0; kk < 2; ++kk) {
        bf16x8 af[FM], bfr[FN];
        #pragma unroll
        for (int m = 0; m < FM; ++m)
          af[m] = lds_frag(As, wm * WM + m * 16 + lr, kk * 4 + lk);
        #pragma unroll
        for (int n = 0; n < FN; ++n)
          bfr[n] = lds_frag(Bs, wn * WN + n * 16 + lr, kk * 4 + lk);
        #pragma unroll
        for (int m = 0; m < FM; ++m)
          #pragma unroll
          for (int n = 0; n < FN; ++n)
            acc[m][n] = __builtin_amdgcn_mfma_f32_16x16x32_bf16(af[m], bfr[n], acc[m][n], 0, 0, 0);
      }
    }
  }
  if constexpr (EPI == 3) {
    // ---- fused RoPE + scatter (qkv GEMM only; BM=BN=64) ----
    __syncthreads();                 // all waves done reading staging LDS
    auto ct = (float (*)[66])smem;
    #pragma unroll
    for (int m = 0; m < FM; ++m)
      #pragma unroll
      for (int n = 0; n < FN; ++n)
        #pragma unroll
        for (int i = 0; i < 4; ++i)
          ct[wm * WM + m * 16 + lk * 4 + i][wn * WN + n * 16 + lr] = acc[m][n][i];
    __syncthreads();
    const int r = tid >> 2, quad = tid & 3;
    const int tr = bm + r;
    int b, pos, catrow;
    if (tr < RSUM) { b = tr >> 6; pos = tr & (NB - 1); catrow = pos; }
    else { const int rr = tr - RSUM; b = rr >> 10; pos = rr & (SEQ - 1); catrow = NB + pos; }
    const int part = bn >> 9;              // 0=Q, 1=K, 2=V
    const int head = (bn & 511) >> 6;
    const size_t obase = ((size_t)(b * NHEAD + head) * KTOT + catrow) * DHEAD + quad * 16;
    union { unsigned short u[16]; uint4 q[2]; } ob;
    if (part == 2) {
      #pragma unroll
      for (int j = 0; j < 16; ++j) ob.u[j] = f2bf(ct[r][quad * 16 + j]);
      *(uint4*)&vcat[obase] = ob.q[0];
      *(uint4*)&vcat[obase + 8] = ob.q[1];
    } else {
      #pragma unroll
      for (int j = 0; j < 16; ++j) {
        const int d = quad * 16 + j;
        const float v = ct[r][d];
        const float other = ct[r][d ^ 32];
        const float cs = cost[pos * 32 + (d & 31)];
        const float sn = sint[pos * 32 + (d & 31)];
        ob.u[j] = f2bf((d < 32) ? (v * cs - other * sn) : (other * sn + v * cs));
      }
      unsigned short* dst = part ? kcat : (unsigned short*)Cout;
      *(uint4*)&dst[obase] = ob.q[0];
      *(uint4*)&dst[obase + 8] = ob.q[1];
    }
    return;
  }
  #pragma unroll
  for (int m = 0; m < FM; ++m)
    #pragma unroll
    for (int n = 0; n < FN; ++n)
      #pragma unroll
      for (int i = 0; i < 4; ++i) {
        int row = bm + wm * WM + m * 16 + lk * 4 + i;
        int col = bn + wn * WN + n * 16 + lr;
        float v = acc[m][n][i];
        if constexpr (EPI == 1) {
          const float other = __shfl_xor(v, 1, 64);
          if (!(lr & 1)) {
            const float g = v, u = other;
            const float hv = (g / (1.f + __expf(-g))) * u;
            unsigned short* C = (unsigned short*)Cout;
            C[(size_t)row * (N >> 1) + (col >> 1)] = f2bf(hv);
          }
        } else if constexpr (EPI == 2) {
          unsigned short* C = (unsigned short*)Cout;
          C[(size_t)row * N + col] = f2bf(v);
        } else {
          float* C = (float*)Cout;
          size_t idx = (size_t)row * N + col;
          if (resid) v += resid[idx];
          C[idx] = v;
        }
      }
}

// ---------------- weight transpose + fp32->bf16 (v2: vectorized IO) -------
// 64x64 tiles; read = float4 (16B/lane), write = 2x uint4 (32B/lane).
// fam = blockIdx.z / nlayer selects src/dst; dst row = n * rmul + radd[fam].
__global__ __launch_bounds__(256) void transpose_conv4_kernel(
    const float* __restrict__ s0, const float* __restrict__ s1,
    const float* __restrict__ s2, const float* __restrict__ s3,
    unsigned short* d0, unsigned short* d1,
    unsigned short* d2, unsigned short* d3,
    int K, int N, size_t sstride,
    size_t ds0, size_t ds1, size_t ds2, size_t ds3,
    int rmul, int4 radds, int nlayer)
{
  __shared__ float tile[64][65];
  const int fam = blockIdx.z / nlayer, l = blockIdx.z % nlayer;
  const float* s = (fam == 0 ? s0 : fam == 1 ? s1 : fam == 2 ? s2 : s3)
                   + (size_t)l * sstride;
  unsigned short* d = (fam == 0 ? d0 : fam == 1 ? d1 : fam == 2 ? d2 : d3)
                   + (size_t)l * (fam == 0 ? ds0 : fam == 1 ? ds1 : fam == 2 ? ds2 : ds3);
  const int radd = fam == 0 ? radds.x : fam == 1 ? radds.y : fam == 2 ? radds.z : radds.w;
  const int k0 = blockIdx.y * 64, n0 = blockIdx.x * 64;
  const int rr = threadIdx.x >> 4, c4 = threadIdx.x & 15;
  #pragma unroll
  for (int it = 0; it < 4; ++it) {
    const int r = rr + it * 16;
    *(float4*)&tile[r][c4 * 4] = *(const float4*)&s[(size_t)(k0 + r) * N + n0 + c4 * 4];
  }
  __syncthreads();
  const int n = threadIdx.x >> 2, j = threadIdx.x & 3;
  union { unsigned short u[16]; uint4 q[2]; } ob;
  #pragma unroll
  for (int i = 0; i < 16; ++i) ob.u[i] = f2bf(tile[j * 16 + i][n]);
  unsigned short* drow = d + ((size_t)(n0 + n) * rmul + radd) * K + k0 + j * 16;
  *(uint4*)&drow[0] = ob.q[0];
  *(uint4*)&drow[8] = ob.q[1];
}

__global__ __launch_bounds__(256) void convert_bf16_kernel(
    const float* __restrict__ src, unsigned short* __restrict__ dst)
{
  const int i = (blockIdx.x * 256 + threadIdx.x) * 4;
  const float4 v = *(const float4*)&src[i];
  union { unsigned short u[4]; uint2 q; } o;
  o.u[0] = f2bf(v.x); o.u[1] = f2bf(v.y); o.u[2] = f2bf(v.z); o.u[3] = f2bf(v.w);
  *(uint2*)&dst[i] = o.q;
}

// ---------------- embedding init ------------------------------------------
__global__ __launch_bounds__(128) void embed_kernel(
    const int* __restrict__ tok, const int* __restrict__ inst,
    const float* __restrict__ tok_emb, const float* __restrict__ inst_emb,
    const float* __restrict__ bar_emb, float* __restrict__ z)
{
  const int r = blockIdx.x, t = threadIdx.x;
  float4 val;
  if (r < RSUM) {
    const int bar = r & (NB - 1);
    val = *(const float4*)&bar_emb[(size_t)bar * DMODEL + t * 4];
  } else {
    const int rr = r - RSUM;
    const int b = rr >> 10, i = rr & (SEQ - 1);
    const int tk = tok[b * SEQ + i];
    int ins = inst[b * SEQ + i];
    ins = ins < 0 ? 0 : (ins > 129 ? 129 : ins);
    const float4 a = *(const float4*)&tok_emb[(size_t)tk * DMODEL + t * 4];
    const float4 cc = *(const float4*)&inst_emb[(size_t)ins * DMODEL + t * 4];
    val.x = a.x + cc.x; val.y = a.y + cc.y; val.z = a.z + cc.z; val.w = a.w + cc.w;
  }
  *(float4*)&z[(size_t)r * DMODEL + t * 4] = val;
}

// ---------------- LayerNorm (one wave per row, D=512) ----------------------
__global__ __launch_bounds__(256) void ln_dual_kernel(
    const float* __restrict__ x, const float* __restrict__ g_s,
    const float* __restrict__ b_s, const float* __restrict__ g_r,
    const float* __restrict__ b_r, unsigned short* __restrict__ out)
{
  const int wid = threadIdx.x >> 6, lane = threadIdx.x & 63;
  const size_t row = (size_t)blockIdx.x * 4 + wid;
  const float* g = (row < RSUM) ? g_s : g_r;
  const float* bb = (row < RSUM) ? b_s : b_r;
  const float* xr = x + row * DMODEL + lane * 8;
  float v[8];
  *(float4*)&v[0] = *(const float4*)&xr[0];
  *(float4*)&v[4] = *(const float4*)&xr[4];
  float s = 0.f;
  #pragma unroll
  for (int j = 0; j < 8; ++j) s += v[j];
  #pragma unroll
  for (int o = 32; o > 0; o >>= 1) s += __shfl_xor(s, o, 64);
  const float mean = s * (1.f / DMODEL);
  float vs = 0.f;
  #pragma unroll
  for (int j = 0; j < 8; ++j) { float d = v[j] - mean; vs += d * d; }
  #pragma unroll
  for (int o = 32; o > 0; o >>= 1) vs += __shfl_xor(vs, o, 64);
  const float rs = rsqrtf(vs * (1.f / DMODEL) + 1e-5f);
  float gg[8], bv[8];
  *(float4*)&gg[0] = *(const float4*)&g[lane * 8];
  *(float4*)&gg[4] = *(const float4*)&g[lane * 8 + 4];
  *(float4*)&bv[0] = *(const float4*)&bb[lane * 8];
  *(float4*)&bv[4] = *(const float4*)&bb[lane * 8 + 4];
  union { unsigned short u[8]; uint4 q; } o8;
  #pragma unroll
  for (int j = 0; j < 8; ++j) o8.u[j] = f2bf((v[j] - mean) * rs * gg[j] + bv[j]);
  *(uint4*)&out[row * DMODEL + lane * 8] = o8.q;
}

__global__ __launch_bounds__(256) void ln_kernel(
    const float* __restrict__ x, const float* __restrict__ g,
    const float* __restrict__ bb, unsigned short* __restrict__ out)
{
  const int wid = threadIdx.x >> 6, lane = threadIdx.x & 63;
  const size_t row = (size_t)blockIdx.x * 4 + wid;
  const float* xr = x + row * DMODEL + lane * 8;
  float v[8];
  *(float4*)&v[0] = *(const float4*)&xr[0];
  *(float4*)&v[4] = *(const float4*)&xr[4];
  float s = 0.f;
  #pragma unroll
  for (int j = 0; j < 8; ++j) s += v[j];
  #pragma unroll
  for (int o = 32; o > 0; o >>= 1) s += __shfl_xor(s, o, 64);
  const float mean = s * (1.f / DMODEL);
  float vs = 0.f;
  #pragma unroll
  for (int j = 0; j < 8; ++j) { float d = v[j] - mean; vs += d * d; }
  #pragma unroll
  for (int o = 32; o > 0; o >>= 1) vs += __shfl_xor(vs, o, 64);
  const float rs = rsqrtf(vs * (1.f / DMODEL) + 1e-5f);
  float gg[8], bv[8];
  *(float4*)&gg[0] = *(const float4*)&g[lane * 8];
  *(float4*)&gg[4] = *(const float4*)&g[lane * 8 + 4];
  *(float4*)&bv[0] = *(const float4*)&bb[lane * 8];
  *(float4*)&bv[4] = *(const float4*)&bb[lane * 8 + 4];
  union { unsigned short u[8]; uint4 q; } o8;
  #pragma unroll
  for (int j = 0; j < 8; ++j) o8.u[j] = f2bf((v[j] - mean) * rs * gg[j] + bv[j]);
  *(uint4*)&out[row * DMODEL + lane * 8] = o8.q;
}

// ---------------- RoPE tables & segment boundaries -------------------------
__global__ void rope_table_kernel(float* __restrict__ cost, float* __restrict__ sint) {
  const int pos = blockIdx.x, j = threadIdx.x;  // block 32
  const float inv = powf(10000.f, -(float)j / 32.f);
  const float f = (float)pos * inv;
  cost[pos * 32 + j] = cosf(f);
  sint[pos * 32 + j] = sinf(f);
}

__global__ void segstart_kernel(const int* __restrict__ chord, int* __restrict__ seg) {
  const int b = blockIdx.x, t = threadIdx.x;  // block 128, chord sorted ascending
  if (t <= NB) {
    int lo = 0, hi = SEQ;
    while (lo < hi) {
      int mid = (lo + hi) >> 1;
      if (chord[b * SEQ + mid] < t) lo = mid + 1; else hi = mid;
    }
    seg[b * (NB + 1) + t] = lo;
  }
}

// ---------------- sparse attention: one WAVE per query, 64-key tiles -------
// K/V/Q in bf16. Phase 1: 4 lanes per key (lane&3 = 16-elem chunk of d);
// dot reduced by 2 shfl_xor; ONE wave-max + ONE wave-sum per tile.
// Phase 2: lane = (kk,dd) = 4 key-groups x 16 d-quads; 16 bf16x4 V loads,
// 4 independent FMA chains; cross-kk reduce via 2 shfl_xor at the end.
__global__ __launch_bounds__(256) void attn_kernel(
    const unsigned short* __restrict__ q_cat, const unsigned short* __restrict__ k_cat,
    const unsigned short* __restrict__ v_cat, const int* __restrict__ seg,
    const int* __restrict__ chord, unsigned short* __restrict__ att)
{
  const int h = blockIdx.y, b = blockIdx.z;
  const int wid = threadIdx.x >> 6, lane = threadIdx.x & 63;
  const int qi = blockIdx.x * 4 + wid;            // 0..1087
  int qrow, nsum, s0, nk, outrow;
  if (qi < NB) {
    const int c = qi;
    s0 = seg[b * (NB + 1) + c];
    const int s1 = seg[b * (NB + 1) + c + 1];
    qrow = c; nsum = c + 1; nk = nsum + (s1 - s0);
    outrow = b * NB + c;
  } else {
    const int i = qi - NB;
    const int c = chord[b * SEQ + i];
    s0 = seg[b * (NB + 1) + c];
    qrow = NB + i; nsum = c; nk = nsum + (i - s0 + 1);
    outrow = RSUM + b * SEQ + i;
  }
  const size_t bh = (size_t)(b * NHEAD + h) * KTOT * DHEAD;
  const unsigned short* __restrict__ Kp = k_cat + bh;
  const unsigned short* __restrict__ Vp = v_cat + bh;
  __shared__ __align__(16) float qsh[4][DHEAD];
  __shared__ __align__(16) float psh[4][64];
  qsh[wid][lane] = bf2f(q_cat[bh + (size_t)qrow * DHEAD + lane]) * 0.125f;
  const int lq = lane & 3;            // phase1: 16-elem chunk of d
  const int lkey = lane >> 2;         // phase1: key within 16-key group
  const int kk = lane >> 4;           // phase2: key group (0..3)
  const int dd = lane & 15;           // phase2: d quad (0..15)
  float m = -1e30f, l = 0.f;
  float4 o4 = {0.f, 0.f, 0.f, 0.f};
  for (int t0 = 0; t0 < nk; t0 += 64) {
    // ---- phase 1: scores for 64 keys (4 passes x 16 keys) ----
    float sv[4];
    float tmax = -3.0e38f;
    #pragma unroll
    for (int pass = 0; pass < 4; ++pass) {
      const int t = t0 + pass * 16 + lkey;
      int kr = (t < nsum) ? t : (NB + s0 + (t - nsum));
      if (kr > KTOT - 1) kr = KTOT - 1;          // clamp invalid lanes
      const bf16x8* krp = (const bf16x8*)(Kp + (size_t)kr * DHEAD + lq * 16);
      const bf16x8 k0v = krp[0], k1v = krp[1];
      float a = 0.f;
      #pragma unroll
      for (int d2 = 0; d2 < 8; ++d2)
        a = fmaf(qsh[wid][lq * 16 + d2], bf2f((unsigned short)k0v[d2]), a);
      #pragma unroll
      for (int d2 = 0; d2 < 8; ++d2)
        a = fmaf(qsh[wid][lq * 16 + 8 + d2], bf2f((unsigned short)k1v[d2]), a);
      a += __shfl_xor(a, 1, 64);
      a += __shfl_xor(a, 2, 64);                 // full dot at all 4 lanes
      sv[pass] = (t < nk) ? a : -3.0e38f;
      tmax = fmaxf(tmax, sv[pass]);
    }
    #pragma unroll
    for (int off = 32; off > 0; off >>= 1) tmax = fmaxf(tmax, __shfl_xor(tmax, off, 64));
    const float mn = fmaxf(m, tmax);
    float psum = 0.f;
    #pragma unroll
    for (int pass = 0; pass < 4; ++pass) {
      const float pp = __expf(sv[pass] - mn);    // exp(-huge) -> 0 for masked
      psum += pp;
      if (lq == 0) psh[wid][pass * 16 + lkey] = pp;
    }
    psum *= 0.25f;                               // each key counted by 4 lanes
    #pragma unroll
    for (int off = 32; off > 0; off >>= 1) psum += __shfl_xor(psum, off, 64);
    const float scale = __expf(m - mn);
    l = l * scale + psum;
    o4.x *= scale; o4.y *= scale; o4.z *= scale; o4.w *= scale;
    m = mn;
    // ---- phase 2: PV accumulate, 16 keys per lane, bf16x4 V loads ----
    #pragma unroll
    for (int j = 0; j < 16; ++j) {
      const int toff = j * 4 + kk;
      const float p = psh[wid][toff];            // broadcast within kk group
      const int tk = t0 + toff;
      int kr = (tk < nsum) ? tk : (NB + s0 + (tk - nsum));
      if (kr > KTOT - 1) kr = KTOT - 1;          // p==0 for padded keys
      const bf16x4 vv = *(const bf16x4*)&Vp[(size_t)kr * DHEAD + dd * 4];
      o4.x = fmaf(p, bf2f((unsigned short)vv[0]), o4.x);
      o4.y = fmaf(p, bf2f((unsigned short)vv[1]), o4.y);
      o4.z = fmaf(p, bf2f((unsigned short)vv[2]), o4.z);
      o4.w = fmaf(p, bf2f((unsigned short)vv[3]), o4.w);
    }
  }
  // reduce over the 4 key groups (lanes l, l^16, l^32, l^48)
  #pragma unroll
  for (int off = 16; off <= 32; off <<= 1) {
    o4.x += __shfl_xor(o4.x, off, 64);
    o4.y += __shfl_xor(o4.y, off, 64);
    o4.z += __shfl_xor(o4.z, off, 64);
    o4.w += __shfl_xor(o4.w, off, 64);
  }
  if (kk == 0) {
    const float invl = 1.f / l;
    union { unsigned short u[4]; uint2 q; } ob;
    ob.u[0] = f2bf(o4.x * invl); ob.u[1] = f2bf(o4.y * invl);
    ob.u[2] = f2bf(o4.z * invl); ob.u[3] = f2bf(o4.w * invl);
    *(uint2*)&att[(size_t)outrow * DMODEL + h * DHEAD + dd * 4] = ob.q;
  }
}

// ===========================================================================
extern "C" void kernel_launch(void* const* d_in, const int* in_sizes, int n_in,
                              void* d_out, int out_size, void* d_ws, size_t ws_size,
                              hipStream_t stream)
{
  const int* tok      = (const int*)d_in[0];
  const int* chord    = (const int*)d_in[1];
  const int* inst     = (const int*)d_in[2];
  const float* tok_emb  = (const float*)d_in[4];
  const float* inst_emb = (const float*)d_in[5];
  const float* bar_emb  = (const float*)d_in[6];
  const float* ln_as_g = (const float*)d_in[7];
  const float* ln_as_b = (const float*)d_in[8];
  const float* ln_ar_g = (const float*)d_in[9];
  const float* ln_ar_b = (const float*)d_in[10];
  const float* ln_fs_g = (const float*)d_in[11];
  const float* ln_fs_b = (const float*)d_in[12];
  const float* ln_fr_g = (const float*)d_in[13];
  const float* ln_fr_b = (const float*)d_in[14];
  const float* Wq = (const float*)d_in[15];
  const float* Wk = (const float*)d_in[16];
  const float* Wv = (const float*)d_in[17];
  const float* Wo = (const float*)d_in[18];
  const float* fs_w1 = (const float*)d_in[19];
  const float* fs_w3 = (const float*)d_in[20];
  const float* fs_w2 = (const float*)d_in[21];
  const float* fr_w1 = (const float*)d_in[22];
  const float* fr_w3 = (const float*)d_in[23];
  const float* fr_w2 = (const float*)d_in[24];
  const float* out_g = (const float*)d_in[25];
  const float* out_b = (const float*)d_in[26];

  char* p = (char*)d_ws;
  auto alloc = [&](size_t bytes) -> void* {
    void* r = (void*)p;
    p += (bytes + 255) & ~(size_t)255;
    return r;
  };
  unsigned short* WqkvT  = (unsigned short*)alloc((size_t)NLAYER * 1536 * 512 * 2);
  unsigned short* WoT    = (unsigned short*)alloc((size_t)NLAYER * 512 * 512 * 2);
  unsigned short* fsW13T = (unsigned short*)alloc((size_t)NLAYER * 4096 * 512 * 2);  // interleaved w1/w3
  unsigned short* frW13T = (unsigned short*)alloc((size_t)NLAYER * 4096 * 512 * 2);  // interleaved w1/w3
  unsigned short* fsW2T  = (unsigned short*)alloc((size_t)NLAYER * 512 * 2048 * 2);
  unsigned short* frW2T  = (unsigned short*)alloc((size_t)NLAYER * 512 * 2048 * 2);
  unsigned short* tokT   = (unsigned short*)alloc((size_t)VOCAB * DMODEL * 2);
  float* z           = (float*)alloc((size_t)RTOT * DMODEL * 4);
  unsigned short* zn = (unsigned short*)alloc((size_t)RTOT * DMODEL * 2);
  unsigned short* q_cat = (unsigned short*)alloc((size_t)BATCH * NHEAD * KTOT * DHEAD * 2);
  unsigned short* k_cat = (unsigned short*)alloc((size_t)BATCH * NHEAD * KTOT * DHEAD * 2);
  unsigned short* v_cat = (unsigned short*)alloc((size_t)BATCH * NHEAD * KTOT * DHEAD * 2);
  unsigned short* att = (unsigned short*)alloc((size_t)RTOT * DMODEL * 2);
  unsigned short* h1 = (unsigned short*)alloc((size_t)RTOT * FDIM * 2);
  float* cost        = (float*)alloc((size_t)SEQ * 32 * 4);
  float* sint        = (float*)alloc((size_t)SEQ * 32 * 4);
  int* seg           = (int*)alloc((size_t)BATCH * (NB + 1) * 4);
  if ((size_t)(p - (char*)d_ws) > ws_size) return;  // ws too small -> fail loudly

  // ---- weight conversion (fp32 -> bf16, [K][N] -> [N][K]; 3 dispatches) ---
  transpose_conv4_kernel<<<dim3(512 / 64, 512 / 64, 4 * NLAYER), 256, 0, stream>>>(
      Wq, Wk, Wv, Wo,
      WqkvT, WqkvT + (size_t)512 * 512, WqkvT + (size_t)1024 * 512, WoT,
      512, 512, (size_t)512 * 512,
      (size_t)1536 * 512, (size_t)1536 * 512, (size_t)1536 * 512, (size_t)512 * 512,
      1, make_int4(0, 0, 0, 0), NLAYER);
  transpose_conv4_kernel<<<dim3(2048 / 64, 512 / 64, 4 * NLAYER), 256, 0, stream>>>(
      fs_w1, fs_w3, fr_w1, fr_w3,
      fsW13T, fsW13T, frW13T, frW13T,
      512, 2048, (size_t)512 * 2048,
      (size_t)4096 * 512, (size_t)4096 * 512, (size_t)4096 * 512, (size_t)4096 * 512,
      2, make_int4(0, 1, 0, 1), NLAYER);
  transpose_conv4_kernel<<<dim3(512 / 64, 2048 / 64, 2 * NLAYER), 256, 0, stream>>>(
      fs_w2, fr_w2, fs_w2, fr_w2,
      fsW2T, frW2T, fsW2T, frW2T,
      2048, 512, (size_t)2048 * 512,
      (size_t)512 * 2048, (size_t)512 * 2048, (size_t)512 * 2048, (size_t)512 * 2048,
      1, make_int4(0, 0, 0, 0), NLAYER);
  convert_bf16_kernel<<<VOCAB * DMODEL / 1024, 256, 0, stream>>>(tok_emb, tokT);

  // ---- setup ----
  embed_kernel<<<RTOT, 128, 0, stream>>>(tok, inst, tok_emb, inst_emb, bar_emb, z);
  rope_table_kernel<<<SEQ, 32, 0, stream>>>(cost, sint);
  segstart_kernel<<<BATCH, 128, 0, stream>>>(chord, seg);

  // ---- layers ----
  for (int l = 0; l < NLAYER; ++l) {
    const size_t ld = (size_t)l * DMODEL;
    // attention block (RoPE+scatter fused into qkv GEMM epilogue)
    ln_dual_kernel<<<RTOT / 4, 256, 0, stream>>>(z, ln_as_g + ld, ln_as_b + ld,
                                                 ln_ar_g + ld, ln_ar_b + ld, zn);
    gemm_bt<64, 64, 3, true><<<dim3(1536 / 64, RTOT / 64), 256, 0, stream>>>(
        zn, WqkvT + (size_t)l * 1536 * 512, WqkvT + (size_t)l * 1536 * 512,
        q_cat, nullptr, 1536, 512, cost, sint, k_cat, v_cat);
    attn_kernel<<<dim3(KTOT / 4, NHEAD, BATCH), 256, 0, stream>>>(q_cat, k_cat, v_cat, seg, chord, att);
    gemm_bt<32, 32, 0, true><<<dim3(512 / 32, RTOT / 32), 256, 0, stream>>>(
        att, WoT + (size_t)l * 512 * 512, WoT + (size_t)l * 512 * 512,
        z, z, 512, 512, nullptr, nullptr, nullptr, nullptr);
    // FFN block (SwiGLU fused into W13 epilogue; fs/fr unified per M-tile)
    ln_dual_kernel<<<RTOT / 4, 256, 0, stream>>>(z, ln_fs_g + ld, ln_fs_b + ld,
                                                 ln_fr_g + ld, ln_fr_b + ld, zn);
    gemm_bt<64, 32, 1, true><<<dim3(4096 / 32, RTOT / 64), 256, 0, stream>>>(
        zn, fsW13T + (size_t)l * 4096 * 512, frW13T + (size_t)l * 4096 * 512,
        h1, nullptr, 4096, 512, nullptr, nullptr, nullptr, nullptr);
    gemm_bt<32, 32, 0, true><<<dim3(512 / 32, RTOT / 32), 256, 0, stream>>>(
        h1, fsW2T + (size_t)l * 512 * 2048, frW2T + (size_t)l * 512 * 2048,
        z, z, 512, 2048, nullptr, nullptr, nullptr, nullptr);
  }

  // ---- final LN + logits ----
  ln_kernel<<<RREG / 4, 256, 0, stream>>>(z + (size_t)RSUM * DMODEL, out_g, out_b,
                                          zn + (size_t)RSUM * DMODEL);
  gemm_bt<32, 32, 0, true><<<dim3(VOCAB / 32, RREG / 32), 256, 0, stream>>>(
      zn + (size_t)RSUM * DMODEL, tokT, tokT, (float*)d_out, nullptr, VOCAB, 512,
      nullptr, nullptr, nullptr, nullptr);
}

// Round 20
// 1213.423 us; speedup vs baseline: 1.0361x; 1.0361x over previous
//
#include <hip/hip_runtime.h>
#include <stdint.h>

#define NB 64
#define BATCH 2
#define SEQ 1024
#define DMODEL 512
#define NHEAD 8
#define DHEAD 64
#define FDIM 2048
#define NLAYER 12
#define VOCAB 1024
#define KTOT (NB + SEQ)          // 1088
#define RSUM (BATCH * NB)        // 128
#define RREG (BATCH * SEQ)       // 2048
#define RTOT (RSUM + RREG)       // 2176

using bf16x8 = __attribute__((ext_vector_type(8))) short;
using bf16x4 = __attribute__((ext_vector_type(4))) short;
using f32x4  = __attribute__((ext_vector_type(4))) float;

__device__ __forceinline__ unsigned short f2bf(float f) {
  union { float f; unsigned u; } c; c.f = f;
  return (unsigned short)((c.u + 0x7fffu + ((c.u >> 16) & 1u)) >> 16);
}
__device__ __forceinline__ float bf2f(unsigned short s) {
  union { unsigned u; float f; } c; c.u = ((unsigned)s) << 16;
  return c.f;
}

// ---- async global->LDS staging of an R x 64-bf16 tile --------------------
// LDS layout linear [R][64]; source pre-swizzled: LDS slot j of row r holds
// global chunk (j ^ (r&7)) (16B chunks). Reads undo the XOR -> conflict-free.
template<int R>
__device__ __forceinline__ void stage_tile(
    const unsigned short* __restrict__ G, int K, int base_row, int k0,
    unsigned short (*lds)[64], int wid, int lane)
{
  const int rl = lane >> 3;
  const int j  = lane & 7;
  #pragma unroll
  for (int c = 0; c < R / 32; ++c) {
    const int r0 = wid * (R / 4) + c * 8;          // wave-uniform
    const int row = r0 + rl;
    const unsigned short* g = G + (size_t)(base_row + row) * K + k0
                                + ((j ^ (row & 7)) << 3);
    __builtin_amdgcn_global_load_lds(
        (const __attribute__((address_space(1))) void*)g,
        (__attribute__((address_space(3))) void*)&lds[r0][0], 16, 0, 0);
  }
}

__device__ __forceinline__ bf16x8 lds_frag(const unsigned short (*lds)[64],
                                           int row, int cc) {
  return *(const bf16x8*)&lds[row][(cc ^ (row & 7)) << 3];
}

// ---------------- GEMM: C[M,N] (+resid) = A[M,K]bf16 @ BT[N,K]bf16^T ------
// Small tiles, 256 threads -> many blocks/CU: latency hides via occupancy.
// PIPE: double-buffered LDS; STAGE(t+1) issued before compute(t).
// Dual-stream: M-tiles with bm < RSUM (summary rows) use B0, others B1.
// EPI: 0 = fp32 (+optional resid), 1 = SwiGLU->bf16 (w1/w3 interleaved,
// row stride N/2), 2 = bf16, 3 = fused RoPE+scatter to q/k/v_cat (BM=BN=64,
// head-aligned tiles; C tile staged via LDS to pair d with d^32).
template<int BM, int BN, int EPI, bool PIPE>
__global__ __launch_bounds__(256) void gemm_bt(
    const unsigned short* __restrict__ A, const unsigned short* __restrict__ B0,
    const unsigned short* __restrict__ B1,
    void* __restrict__ Cout, const float* resid, int N, int K,
    const float* __restrict__ cost, const float* __restrict__ sint,
    unsigned short* __restrict__ kcat, unsigned short* __restrict__ vcat)
{
  constexpr int BK = 64;
  constexpr int WM = BM / 2, WN = BN / 2;
  constexpr int FM = WM / 16, FN = WN / 16;
  constexpr int HALF = (BM + BN) * BK * 2;
  constexpr int SM_STAGE = (PIPE ? 2 : 1) * HALF;
  constexpr int SM_CT = (EPI == 3) ? 64 * 66 * 4 : 0;
  constexpr int SMSZ = SM_STAGE > SM_CT ? SM_STAGE : SM_CT;
  __shared__ __align__(16) unsigned char smem[SMSZ];
  const int bm = blockIdx.y * BM, bn = blockIdx.x * BN;
  const unsigned short* __restrict__ BT = (bm < RSUM) ? B0 : B1;
  const int tid = threadIdx.x;
  const int wid = tid >> 6, lane = tid & 63;
  const int wm = wid >> 1, wn = wid & 1;
  const int lr = lane & 15, lk = lane >> 4;
  f32x4 acc[FM][FN] = {};
  if constexpr (PIPE) {
    auto AsB = [&](int b) { return (unsigned short (*)[BK])(smem + b * HALF); };
    auto BsB = [&](int b) { return (unsigned short (*)[BK])(smem + b * HALF + BM * BK * 2); };
    stage_tile<BM>(A, K, bm, 0, AsB(0), wid, lane);
    stage_tile<BN>(BT, K, bn, 0, BsB(0), wid, lane);
    __syncthreads();
    int cur = 0;
    for (int k0 = 0; k0 < K; k0 += BK) {
      if (k0 + BK < K) {
        stage_tile<BM>(A, K, bm, k0 + BK, AsB(cur ^ 1), wid, lane);
        stage_tile<BN>(BT, K, bn, k0 + BK, BsB(cur ^ 1), wid, lane);
      }
      #pragma unroll
      for (int kk = 0; kk < 2; ++kk) {
        bf16x8 af[FM], bfr[FN];
        #pragma unroll
        for (int m = 0; m < FM; ++m)
          af[m] = lds_frag(AsB(cur), wm * WM + m * 16 + lr, kk * 4 + lk);
        #pragma unroll
        for (int n = 0; n < FN; ++n)
          bfr[n] = lds_frag(BsB(cur), wn * WN + n * 16 + lr, kk * 4 + lk);
        #pragma unroll
        for (int m = 0; m < FM; ++m)
          #pragma unroll
          for (int n = 0; n < FN; ++n)
            acc[m][n] = __builtin_amdgcn_mfma_f32_16x16x32_bf16(af[m], bfr[n], acc[m][n], 0, 0, 0);
      }
      __syncthreads();               // drains prefetch + LDS reads of cur
      cur ^= 1;
    }
  } else {
    auto As = (unsigned short (*)[BK])smem;
    auto Bs = (unsigned short (*)[BK])(smem + BM * BK * 2);
    for (int k0 = 0; k0 < K; k0 += BK) {
      __syncthreads();
      stage_tile<BM>(A, K, bm, k0, As, wid, lane);
      stage_tile<BN>(BT, K, bn, k0, Bs, wid, lane);
      __syncthreads();               // drains vmcnt -> tile ready
      #pragma unroll
      for (int kk = 0; kk < 2; ++kk) {
        bf16x8 af[FM], bfr[FN];
        #pragma unroll
        for (int m = 0; m < FM; ++m)
          af[m] = lds_frag(As, wm * WM + m * 16 + lr, kk * 4 + lk);
        #pragma unroll
        for (int n = 0; n < FN; ++n)
          bfr[n] = lds_frag(Bs, wn * WN + n * 16 + lr, kk * 4 + lk);
        #pragma unroll
        for (int m = 0; m < FM; ++m)
          #pragma unroll
          for (int n = 0; n < FN; ++n)
            acc[m][n] = __builtin_amdgcn_mfma_f32_16x16x32_bf16(af[m], bfr[n], acc[m][n], 0, 0, 0);
      }
    }
  }
  if constexpr (EPI == 3) {
    // ---- fused RoPE + scatter (qkv GEMM only; BM=BN=64) ----
    __syncthreads();                 // all waves done reading staging LDS
    auto ct = (float (*)[66])smem;
    #pragma unroll
    for (int m = 0; m < FM; ++m)
      #pragma unroll
      for (int n = 0; n < FN; ++n)
        #pragma unroll
        for (int i = 0; i < 4; ++i)
          ct[wm * WM + m * 16 + lk * 4 + i][wn * WN + n * 16 + lr] = acc[m][n][i];
    __syncthreads();
    const int r = tid >> 2, quad = tid & 3;
    const int tr = bm + r;
    int b, pos, catrow;
    if (tr < RSUM) { b = tr >> 6; pos = tr & (NB - 1); catrow = pos; }
    else { const int rr = tr - RSUM; b = rr >> 10; pos = rr & (SEQ - 1); catrow = NB + pos; }
    const int part = bn >> 9;              // 0=Q, 1=K, 2=V
    const int head = (bn & 511) >> 6;
    const size_t obase = ((size_t)(b * NHEAD + head) * KTOT + catrow) * DHEAD + quad * 16;
    union { unsigned short u[16]; uint4 q[2]; } ob;
    if (part == 2) {
      #pragma unroll
      for (int j = 0; j < 16; ++j) ob.u[j] = f2bf(ct[r][quad * 16 + j]);
      *(uint4*)&vcat[obase] = ob.q[0];
      *(uint4*)&vcat[obase + 8] = ob.q[1];
    } else {
      #pragma unroll
      for (int j = 0; j < 16; ++j) {
        const int d = quad * 16 + j;
        const float v = ct[r][d];
        const float other = ct[r][d ^ 32];
        const float cs = cost[pos * 32 + (d & 31)];
        const float sn = sint[pos * 32 + (d & 31)];
        ob.u[j] = f2bf((d < 32) ? (v * cs - other * sn) : (other * sn + v * cs));
      }
      unsigned short* dst = part ? kcat : (unsigned short*)Cout;
      *(uint4*)&dst[obase] = ob.q[0];
      *(uint4*)&dst[obase + 8] = ob.q[1];
    }
    return;
  }
  #pragma unroll
  for (int m = 0; m < FM; ++m)
    #pragma unroll
    for (int n = 0; n < FN; ++n)
      #pragma unroll
      for (int i = 0; i < 4; ++i) {
        int row = bm + wm * WM + m * 16 + lk * 4 + i;
        int col = bn + wn * WN + n * 16 + lr;
        float v = acc[m][n][i];
        if constexpr (EPI == 1) {
          const float other = __shfl_xor(v, 1, 64);
          if (!(lr & 1)) {
            const float g = v, u = other;
            const float hv = (g / (1.f + __expf(-g))) * u;
            unsigned short* C = (unsigned short*)Cout;
            C[(size_t)row * (N >> 1) + (col >> 1)] = f2bf(hv);
          }
        } else if constexpr (EPI == 2) {
          unsigned short* C = (unsigned short*)Cout;
          C[(size_t)row * N + col] = f2bf(v);
        } else {
          float* C = (float*)Cout;
          size_t idx = (size_t)row * N + col;
          if (resid) v += resid[idx];
          C[idx] = v;
        }
      }
}

// ---------------- weight transpose + fp32->bf16 (v2: vectorized IO) -------
// 64x64 tiles; read = float4 (16B/lane), write = 2x uint4 (32B/lane).
// fam = blockIdx.z / nlayer selects src/dst; dst row = n * rmul + radd[fam].
__global__ __launch_bounds__(256) void transpose_conv4_kernel(
    const float* __restrict__ s0, const float* __restrict__ s1,
    const float* __restrict__ s2, const float* __restrict__ s3,
    unsigned short* d0, unsigned short* d1,
    unsigned short* d2, unsigned short* d3,
    int K, int N, size_t sstride,
    size_t ds0, size_t ds1, size_t ds2, size_t ds3,
    int rmul, int4 radds, int nlayer)
{
  __shared__ float tile[64][65];
  const int fam = blockIdx.z / nlayer, l = blockIdx.z % nlayer;
  const float* s = (fam == 0 ? s0 : fam == 1 ? s1 : fam == 2 ? s2 : s3)
                   + (size_t)l * sstride;
  unsigned short* d = (fam == 0 ? d0 : fam == 1 ? d1 : fam == 2 ? d2 : d3)
                   + (size_t)l * (fam == 0 ? ds0 : fam == 1 ? ds1 : fam == 2 ? ds2 : ds3);
  const int radd = fam == 0 ? radds.x : fam == 1 ? radds.y : fam == 2 ? radds.z : radds.w;
  const int k0 = blockIdx.y * 64, n0 = blockIdx.x * 64;
  const int rr = threadIdx.x >> 4, c4 = threadIdx.x & 15;
  #pragma unroll
  for (int it = 0; it < 4; ++it) {
    const int r = rr + it * 16;
    *(float4*)&tile[r][c4 * 4] = *(const float4*)&s[(size_t)(k0 + r) * N + n0 + c4 * 4];
  }
  __syncthreads();
  const int n = threadIdx.x >> 2, j = threadIdx.x & 3;
  union { unsigned short u[16]; uint4 q[2]; } ob;
  #pragma unroll
  for (int i = 0; i < 16; ++i) ob.u[i] = f2bf(tile[j * 16 + i][n]);
  unsigned short* drow = d + ((size_t)(n0 + n) * rmul + radd) * K + k0 + j * 16;
  *(uint4*)&drow[0] = ob.q[0];
  *(uint4*)&drow[8] = ob.q[1];
}

__global__ __launch_bounds__(256) void convert_bf16_kernel(
    const float* __restrict__ src, unsigned short* __restrict__ dst)
{
  const int i = (blockIdx.x * 256 + threadIdx.x) * 4;
  const float4 v = *(const float4*)&src[i];
  union { unsigned short u[4]; uint2 q; } o;
  o.u[0] = f2bf(v.x); o.u[1] = f2bf(v.y); o.u[2] = f2bf(v.z); o.u[3] = f2bf(v.w);
  *(uint2*)&dst[i] = o.q;
}

// ---------------- embedding init ------------------------------------------
__global__ __launch_bounds__(128) void embed_kernel(
    const int* __restrict__ tok, const int* __restrict__ inst,
    const float* __restrict__ tok_emb, const float* __restrict__ inst_emb,
    const float* __restrict__ bar_emb, float* __restrict__ z)
{
  const int r = blockIdx.x, t = threadIdx.x;
  float4 val;
  if (r < RSUM) {
    const int bar = r & (NB - 1);
    val = *(const float4*)&bar_emb[(size_t)bar * DMODEL + t * 4];
  } else {
    const int rr = r - RSUM;
    const int b = rr >> 10, i = rr & (SEQ - 1);
    const int tk = tok[b * SEQ + i];
    int ins = inst[b * SEQ + i];
    ins = ins < 0 ? 0 : (ins > 129 ? 129 : ins);
    const float4 a = *(const float4*)&tok_emb[(size_t)tk * DMODEL + t * 4];
    const float4 cc = *(const float4*)&inst_emb[(size_t)ins * DMODEL + t * 4];
    val.x = a.x + cc.x; val.y = a.y + cc.y; val.z = a.z + cc.z; val.w = a.w + cc.w;
  }
  *(float4*)&z[(size_t)r * DMODEL + t * 4] = val;
}

// ---------------- LayerNorm (one wave per row, D=512) ----------------------
__global__ __launch_bounds__(256) void ln_dual_kernel(
    const float* __restrict__ x, const float* __restrict__ g_s,
    const float* __restrict__ b_s, const float* __restrict__ g_r,
    const float* __restrict__ b_r, unsigned short* __restrict__ out)
{
  const int wid = threadIdx.x >> 6, lane = threadIdx.x & 63;
  const size_t row = (size_t)blockIdx.x * 4 + wid;
  const float* g = (row < RSUM) ? g_s : g_r;
  const float* bb = (row < RSUM) ? b_s : b_r;
  const float* xr = x + row * DMODEL + lane * 8;
  float v[8];
  *(float4*)&v[0] = *(const float4*)&xr[0];
  *(float4*)&v[4] = *(const float4*)&xr[4];
  float s = 0.f;
  #pragma unroll
  for (int j = 0; j < 8; ++j) s += v[j];
  #pragma unroll
  for (int o = 32; o > 0; o >>= 1) s += __shfl_xor(s, o, 64);
  const float mean = s * (1.f / DMODEL);
  float vs = 0.f;
  #pragma unroll
  for (int j = 0; j < 8; ++j) { float d = v[j] - mean; vs += d * d; }
  #pragma unroll
  for (int o = 32; o > 0; o >>= 1) vs += __shfl_xor(vs, o, 64);
  const float rs = rsqrtf(vs * (1.f / DMODEL) + 1e-5f);
  float gg[8], bv[8];
  *(float4*)&gg[0] = *(const float4*)&g[lane * 8];
  *(float4*)&gg[4] = *(const float4*)&g[lane * 8 + 4];
  *(float4*)&bv[0] = *(const float4*)&bb[lane * 8];
  *(float4*)&bv[4] = *(const float4*)&bb[lane * 8 + 4];
  union { unsigned short u[8]; uint4 q; } o8;
  #pragma unroll
  for (int j = 0; j < 8; ++j) o8.u[j] = f2bf((v[j] - mean) * rs * gg[j] + bv[j]);
  *(uint4*)&out[row * DMODEL + lane * 8] = o8.q;
}

__global__ __launch_bounds__(256) void ln_kernel(
    const float* __restrict__ x, const float* __restrict__ g,
    const float* __restrict__ bb, unsigned short* __restrict__ out)
{
  const int wid = threadIdx.x >> 6, lane = threadIdx.x & 63;
  const size_t row = (size_t)blockIdx.x * 4 + wid;
  const float* xr = x + row * DMODEL + lane * 8;
  float v[8];
  *(float4*)&v[0] = *(const float4*)&xr[0];
  *(float4*)&v[4] = *(const float4*)&xr[4];
  float s = 0.f;
  #pragma unroll
  for (int j = 0; j < 8; ++j) s += v[j];
  #pragma unroll
  for (int o = 32; o > 0; o >>= 1) s += __shfl_xor(s, o, 64);
  const float mean = s * (1.f / DMODEL);
  float vs = 0.f;
  #pragma unroll
  for (int j = 0; j < 8; ++j) { float d = v[j] - mean; vs += d * d; }
  #pragma unroll
  for (int o = 32; o > 0; o >>= 1) vs += __shfl_xor(vs, o, 64);
  const float rs = rsqrtf(vs * (1.f / DMODEL) + 1e-5f);
  float gg[8], bv[8];
  *(float4*)&gg[0] = *(const float4*)&g[lane * 8];
  *(float4*)&gg[4] = *(const float4*)&g[lane * 8 + 4];
  *(float4*)&bv[0] = *(const float4*)&bb[lane * 8];
  *(float4*)&bv[4] = *(const float4*)&bb[lane * 8 + 4];
  union { unsigned short u[8]; uint4 q; } o8;
  #pragma unroll
  for (int j = 0; j < 8; ++j) o8.u[j] = f2bf((v[j] - mean) * rs * gg[j] + bv[j]);
  *(uint4*)&out[row * DMODEL + lane * 8] = o8.q;
}

// ---------------- RoPE tables & segment boundaries -------------------------
__global__ void rope_table_kernel(float* __restrict__ cost, float* __restrict__ sint) {
  const int pos = blockIdx.x, j = threadIdx.x;  // block 32
  const float inv = powf(10000.f, -(float)j / 32.f);
  const float f = (float)pos * inv;
  cost[pos * 32 + j] = cosf(f);
  sint[pos * 32 + j] = sinf(f);
}

__global__ void segstart_kernel(const int* __restrict__ chord, int* __restrict__ seg) {
  const int b = blockIdx.x, t = threadIdx.x;  // block 128, chord sorted ascending
  if (t <= NB) {
    int lo = 0, hi = SEQ;
    while (lo < hi) {
      int mid = (lo + hi) >> 1;
      if (chord[b * SEQ + mid] < t) lo = mid + 1; else hi = mid;
    }
    seg[b * (NB + 1) + t] = lo;
  }
}

// ---------------- sparse attention: one WAVE per query, 64-key tiles -------
// K/V/Q in bf16. Phase 1: 4 lanes per key (lane&3 = 16-elem chunk of d);
// dot reduced by 2 shfl_xor; ONE wave-max + ONE wave-sum per tile.
// Phase 2: lane = (kk,dd) = 4 key-groups x 16 d-quads; 16 bf16x4 V loads,
// 4 independent FMA chains; cross-kk reduce via 2 shfl_xor at the end.
__global__ __launch_bounds__(256) void attn_kernel(
    const unsigned short* __restrict__ q_cat, const unsigned short* __restrict__ k_cat,
    const unsigned short* __restrict__ v_cat, const int* __restrict__ seg,
    const int* __restrict__ chord, unsigned short* __restrict__ att)
{
  const int h = blockIdx.y, b = blockIdx.z;
  const int wid = threadIdx.x >> 6, lane = threadIdx.x & 63;
  const int qi = blockIdx.x * 4 + wid;            // 0..1087
  int qrow, nsum, s0, nk, outrow;
  if (qi < NB) {
    const int c = qi;
    s0 = seg[b * (NB + 1) + c];
    const int s1 = seg[b * (NB + 1) + c + 1];
    qrow = c; nsum = c + 1; nk = nsum + (s1 - s0);
    outrow = b * NB + c;
  } else {
    const int i = qi - NB;
    const int c = chord[b * SEQ + i];
    s0 = seg[b * (NB + 1) + c];
    qrow = NB + i; nsum = c; nk = nsum + (i - s0 + 1);
    outrow = RSUM + b * SEQ + i;
  }
  const size_t bh = (size_t)(b * NHEAD + h) * KTOT * DHEAD;
  const unsigned short* __restrict__ Kp = k_cat + bh;
  const unsigned short* __restrict__ Vp = v_cat + bh;
  __shared__ __align__(16) float qsh[4][DHEAD];
  __shared__ __align__(16) float psh[4][64];
  qsh[wid][lane] = bf2f(q_cat[bh + (size_t)qrow * DHEAD + lane]) * 0.125f;
  const int lq = lane & 3;            // phase1: 16-elem chunk of d
  const int lkey = lane >> 2;         // phase1: key within 16-key group
  const int kk = lane >> 4;           // phase2: key group (0..3)
  const int dd = lane & 15;           // phase2: d quad (0..15)
  float m = -1e30f, l = 0.f;
  float4 o4 = {0.f, 0.f, 0.f, 0.f};
  for (int t0 = 0; t0 < nk; t0 += 64) {
    // ---- phase 1: scores for 64 keys (4 passes x 16 keys) ----
    float sv[4];
    float tmax = -3.0e38f;
    #pragma unroll
    for (int pass = 0; pass < 4; ++pass) {
      const int t = t0 + pass * 16 + lkey;
      int kr = (t < nsum) ? t : (NB + s0 + (t - nsum));
      if (kr > KTOT - 1) kr = KTOT - 1;          // clamp invalid lanes
      const bf16x8* krp = (const bf16x8*)(Kp + (size_t)kr * DHEAD + lq * 16);
      const bf16x8 k0v = krp[0], k1v = krp[1];
      float a = 0.f;
      #pragma unroll
      for (int d2 = 0; d2 < 8; ++d2)
        a = fmaf(qsh[wid][lq * 16 + d2], bf2f((unsigned short)k0v[d2]), a);
      #pragma unroll
      for (int d2 = 0; d2 < 8; ++d2)
        a = fmaf(qsh[wid][lq * 16 + 8 + d2], bf2f((unsigned short)k1v[d2]), a);
      a += __shfl_xor(a, 1, 64);
      a += __shfl_xor(a, 2, 64);                 // full dot at all 4 lanes
      sv[pass] = (t < nk) ? a : -3.0e38f;
      tmax = fmaxf(tmax, sv[pass]);
    }
    #pragma unroll
    for (int off = 32; off > 0; off >>= 1) tmax = fmaxf(tmax, __shfl_xor(tmax, off, 64));
    const float mn = fmaxf(m, tmax);
    float psum = 0.f;
    #pragma unroll
    for (int pass = 0; pass < 4; ++pass) {
      const float pp = __expf(sv[pass] - mn);    // exp(-huge) -> 0 for masked
      psum += pp;
      if (lq == 0) psh[wid][pass * 16 + lkey] = pp;
    }
    psum *= 0.25f;                               // each key counted by 4 lanes
    #pragma unroll
    for (int off = 32; off > 0; off >>= 1) psum += __shfl_xor(psum, off, 64);
    const float scale = __expf(m - mn);
    l = l * scale + psum;
    o4.x *= scale; o4.y *= scale; o4.z *= scale; o4.w *= scale;
    m = mn;
    // ---- phase 2: PV accumulate, 16 keys per lane, bf16x4 V loads ----
    #pragma unroll
    for (int j = 0; j < 16; ++j) {
      const int toff = j * 4 + kk;
      const float p = psh[wid][toff];            // broadcast within kk group
      const int tk = t0 + toff;
      int kr = (tk < nsum) ? tk : (NB + s0 + (tk - nsum));
      if (kr > KTOT - 1) kr = KTOT - 1;          // p==0 for padded keys
      const bf16x4 vv = *(const bf16x4*)&Vp[(size_t)kr * DHEAD + dd * 4];
      o4.x = fmaf(p, bf2f((unsigned short)vv[0]), o4.x);
      o4.y = fmaf(p, bf2f((unsigned short)vv[1]), o4.y);
      o4.z = fmaf(p, bf2f((unsigned short)vv[2]), o4.z);
      o4.w = fmaf(p, bf2f((unsigned short)vv[3]), o4.w);
    }
  }
  // reduce over the 4 key groups (lanes l, l^16, l^32, l^48)
  #pragma unroll
  for (int off = 16; off <= 32; off <<= 1) {
    o4.x += __shfl_xor(o4.x, off, 64);
    o4.y += __shfl_xor(o4.y, off, 64);
    o4.z += __shfl_xor(o4.z, off, 64);
    o4.w += __shfl_xor(o4.w, off, 64);
  }
  if (kk == 0) {
    const float invl = 1.f / l;
    union { unsigned short u[4]; uint2 q; } ob;
    ob.u[0] = f2bf(o4.x * invl); ob.u[1] = f2bf(o4.y * invl);
    ob.u[2] = f2bf(o4.z * invl); ob.u[3] = f2bf(o4.w * invl);
    *(uint2*)&att[(size_t)outrow * DMODEL + h * DHEAD + dd * 4] = ob.q;
  }
}

// ===========================================================================
extern "C" void kernel_launch(void* const* d_in, const int* in_sizes, int n_in,
                              void* d_out, int out_size, void* d_ws, size_t ws_size,
                              hipStream_t stream)
{
  const int* tok      = (const int*)d_in[0];
  const int* chord    = (const int*)d_in[1];
  const int* inst     = (const int*)d_in[2];
  const float* tok_emb  = (const float*)d_in[4];
  const float* inst_emb = (const float*)d_in[5];
  const float* bar_emb  = (const float*)d_in[6];
  const float* ln_as_g = (const float*)d_in[7];
  const float* ln_as_b = (const float*)d_in[8];
  const float* ln_ar_g = (const float*)d_in[9];
  const float* ln_ar_b = (const float*)d_in[10];
  const float* ln_fs_g = (const float*)d_in[11];
  const float* ln_fs_b = (const float*)d_in[12];
  const float* ln_fr_g = (const float*)d_in[13];
  const float* ln_fr_b = (const float*)d_in[14];
  const float* Wq = (const float*)d_in[15];
  const float* Wk = (const float*)d_in[16];
  const float* Wv = (const float*)d_in[17];
  const float* Wo = (const float*)d_in[18];
  const float* fs_w1 = (const float*)d_in[19];
  const float* fs_w3 = (const float*)d_in[20];
  const float* fs_w2 = (const float*)d_in[21];
  const float* fr_w1 = (const float*)d_in[22];
  const float* fr_w3 = (const float*)d_in[23];
  const float* fr_w2 = (const float*)d_in[24];
  const float* out_g = (const float*)d_in[25];
  const float* out_b = (const float*)d_in[26];

  char* p = (char*)d_ws;
  auto alloc = [&](size_t bytes) -> void* {
    void* r = (void*)p;
    p += (bytes + 255) & ~(size_t)255;
    return r;
  };
  unsigned short* WqkvT  = (unsigned short*)alloc((size_t)NLAYER * 1536 * 512 * 2);
  unsigned short* WoT    = (unsigned short*)alloc((size_t)NLAYER * 512 * 512 * 2);
  unsigned short* fsW13T = (unsigned short*)alloc((size_t)NLAYER * 4096 * 512 * 2);  // interleaved w1/w3
  unsigned short* frW13T = (unsigned short*)alloc((size_t)NLAYER * 4096 * 512 * 2);  // interleaved w1/w3
  unsigned short* fsW2T  = (unsigned short*)alloc((size_t)NLAYER * 512 * 2048 * 2);
  unsigned short* frW2T  = (unsigned short*)alloc((size_t)NLAYER * 512 * 2048 * 2);
  unsigned short* tokT   = (unsigned short*)alloc((size_t)VOCAB * DMODEL * 2);
  float* z           = (float*)alloc((size_t)RTOT * DMODEL * 4);
  unsigned short* zn = (unsigned short*)alloc((size_t)RTOT * DMODEL * 2);
  unsigned short* q_cat = (unsigned short*)alloc((size_t)BATCH * NHEAD * KTOT * DHEAD * 2);
  unsigned short* k_cat = (unsigned short*)alloc((size_t)BATCH * NHEAD * KTOT * DHEAD * 2);
  unsigned short* v_cat = (unsigned short*)alloc((size_t)BATCH * NHEAD * KTOT * DHEAD * 2);
  unsigned short* att = (unsigned short*)alloc((size_t)RTOT * DMODEL * 2);
  unsigned short* h1 = (unsigned short*)alloc((size_t)RTOT * FDIM * 2);
  float* cost        = (float*)alloc((size_t)SEQ * 32 * 4);
  float* sint        = (float*)alloc((size_t)SEQ * 32 * 4);
  int* seg           = (int*)alloc((size_t)BATCH * (NB + 1) * 4);
  if ((size_t)(p - (char*)d_ws) > ws_size) return;  // ws too small -> fail loudly

  // ---- weight conversion (fp32 -> bf16, [K][N] -> [N][K]; 3 dispatches) ---
  transpose_conv4_kernel<<<dim3(512 / 64, 512 / 64, 4 * NLAYER), 256, 0, stream>>>(
      Wq, Wk, Wv, Wo,
      WqkvT, WqkvT + (size_t)512 * 512, WqkvT + (size_t)1024 * 512, WoT,
      512, 512, (size_t)512 * 512,
      (size_t)1536 * 512, (size_t)1536 * 512, (size_t)1536 * 512, (size_t)512 * 512,
      1, make_int4(0, 0, 0, 0), NLAYER);
  transpose_conv4_kernel<<<dim3(2048 / 64, 512 / 64, 4 * NLAYER), 256, 0, stream>>>(
      fs_w1, fs_w3, fr_w1, fr_w3,
      fsW13T, fsW13T, frW13T, frW13T,
      512, 2048, (size_t)512 * 2048,
      (size_t)4096 * 512, (size_t)4096 * 512, (size_t)4096 * 512, (size_t)4096 * 512,
      2, make_int4(0, 1, 0, 1), NLAYER);
  transpose_conv4_kernel<<<dim3(512 / 64, 2048 / 64, 2 * NLAYER), 256, 0, stream>>>(
      fs_w2, fr_w2, fs_w2, fr_w2,
      fsW2T, frW2T, fsW2T, frW2T,
      2048, 512, (size_t)2048 * 512,
      (size_t)512 * 2048, (size_t)512 * 2048, (size_t)512 * 2048, (size_t)512 * 2048,
      1, make_int4(0, 0, 0, 0), NLAYER);
  convert_bf16_kernel<<<VOCAB * DMODEL / 1024, 256, 0, stream>>>(tok_emb, tokT);

  // ---- setup ----
  embed_kernel<<<RTOT, 128, 0, stream>>>(tok, inst, tok_emb, inst_emb, bar_emb, z);
  rope_table_kernel<<<SEQ, 32, 0, stream>>>(cost, sint);
  segstart_kernel<<<BATCH, 128, 0, stream>>>(chord, seg);

  // ---- layers ----
  for (int l = 0; l < NLAYER; ++l) {
    const size_t ld = (size_t)l * DMODEL;
    // attention block (RoPE+scatter fused into qkv GEMM epilogue)
    ln_dual_kernel<<<RTOT / 4, 256, 0, stream>>>(z, ln_as_g + ld, ln_as_b + ld,
                                                 ln_ar_g + ld, ln_ar_b + ld, zn);
    gemm_bt<64, 64, 3, true><<<dim3(1536 / 64, RTOT / 64), 256, 0, stream>>>(
        zn, WqkvT + (size_t)l * 1536 * 512, WqkvT + (size_t)l * 1536 * 512,
        q_cat, nullptr, 1536, 512, cost, sint, k_cat, v_cat);
    attn_kernel<<<dim3(KTOT / 4, NHEAD, BATCH), 256, 0, stream>>>(q_cat, k_cat, v_cat, seg, chord, att);
    gemm_bt<32, 32, 0, true><<<dim3(512 / 32, RTOT / 32), 256, 0, stream>>>(
        att, WoT + (size_t)l * 512 * 512, WoT + (size_t)l * 512 * 512,
        z, z, 512, 512, nullptr, nullptr, nullptr, nullptr);
    // FFN block (SwiGLU fused into W13 epilogue; fs/fr unified per M-tile)
    ln_dual_kernel<<<RTOT / 4, 256, 0, stream>>>(z, ln_fs_g + ld, ln_fs_b + ld,
                                                 ln_fr_g + ld, ln_fr_b + ld, zn);
    gemm_bt<64, 64, 1, false><<<dim3(4096 / 64, RTOT / 64), 256, 0, stream>>>(
        zn, fsW13T + (size_t)l * 4096 * 512, frW13T + (size_t)l * 4096 * 512,
        h1, nullptr, 4096, 512, nullptr, nullptr, nullptr, nullptr);
    gemm_bt<32, 32, 0, true><<<dim3(512 / 32, RTOT / 32), 256, 0, stream>>>(
        h1, fsW2T + (size_t)l * 512 * 2048, frW2T + (size_t)l * 512 * 2048,
        z, z, 512, 2048, nullptr, nullptr, nullptr, nullptr);
  }

  // ---- final LN + logits ----
  ln_kernel<<<RREG / 4, 256, 0, stream>>>(z + (size_t)RSUM * DMODEL, out_g, out_b,
                                          zn + (size_t)RSUM * DMODEL);
  gemm_bt<32, 32, 0, true><<<dim3(VOCAB / 32, RREG / 32), 256, 0, stream>>>(
      zn + (size_t)RSUM * DMODEL, tokT, tokT, (float*)d_out, nullptr, VOCAB, 512,
      nullptr, nullptr, nullptr, nullptr);
}